// Round 2
// baseline (88.496 us; speedup 1.0000x reference)
//
#include <hip/hip_runtime.h>
#include <stdint.h>

// Problem constants (fixed by the reference)
#define INF    8192
#define OUTF   8192
#define NOUT   64
#define NG     256          // 3-bit groups along input dim (INF/32)
#define BLK    512          // threads per block (8 waves)
#define COLS   32           // output columns per block -> 128B coalesced lines
#define KC     16           // K-split factor within block (BLK/COLS)
#define GPT    (NG / KC)    // groups per thread = 16

__global__ __launch_bounds__(BLK) void q3gemv(
    const float* __restrict__ x,       // f32 [INF]
    const int*   __restrict__ qw,      // [NG*3, OUTF] packed 3-bit
    const float* __restrict__ scales,  // f32 [OUTF]
    const float* __restrict__ zeros,   // f32 [OUTF]
    const float* __restrict__ bias,    // f32 [OUTF]
    const float* __restrict__ ow,      // f32 [OUTF, NOUT]
    const int*   __restrict__ oidx,    // [NOUT]
    float*       __restrict__ out)     // f32 [OUTF]
{
    __shared__ __align__(16) float xs[INF];    // x staged, 32 KB
    __shared__ float psum[KC][COLS];           // per-k-chunk partials
    __shared__ float xo[NOUT];                 // gathered outlier x
    __shared__ float wsum[BLK / 64];           // per-wave x sums

    const int t     = threadIdx.x;
    const int col   = t & (COLS - 1);
    const int kc    = t >> 5;                  // 0..15
    const int obase = blockIdx.x * COLS;

    // ---- stage x into LDS (float4 coalesced), accumulate Sx on the side ----
    float lsum = 0.f;
    const float4* xv = (const float4*)x;
    #pragma unroll
    for (int k = 0; k < INF / (BLK * 4); ++k) {   // 4 float4 loads/thread
        float4 v = xv[t + k * BLK];
        ((float4*)xs)[t + k * BLK] = v;
        lsum += (v.x + v.y) + (v.z + v.w);
    }
    #pragma unroll
    for (int off = 32; off > 0; off >>= 1)
        lsum += __shfl_down(lsum, off, 64);
    if ((t & 63) == 0) wsum[t >> 6] = lsum;
    __syncthreads();

    // gather outlier x values from LDS (visible after the 2nd barrier)
    if (t < NOUT) xo[t] = xs[oidx[t]];

    // ---- main loop: column (obase+col), groups [kc*GPT, kc*GPT+GPT) ----
    const unsigned* qp = (const unsigned*)qw + (size_t)(kc * GPT * 3) * OUTF + (obase + col);
    const float*    xg = xs + kc * GPT * 32;

    unsigned r0 = qp[0], r1 = qp[OUTF], r2 = qp[2 * OUTF];
    float acc[4] = {0.f, 0.f, 0.f, 0.f};

    #pragma unroll 4
    for (int gg = 0; gg < GPT; ++gg) {
        // prefetch next group's three packed dwords (clamped on last iter)
        const unsigned* qn = qp + ((gg + 1 < GPT) ? (size_t)3 * OUTF : 0);
        unsigned n0 = qn[0], n1 = qn[OUTF], n2 = qn[2 * OUTF];

        // pull this group's 32 x values into registers via ds_read_b128
        float xr[32];
        #pragma unroll
        for (int j = 0; j < 8; ++j) {
            float4 tv = ((const float4*)xg)[j];
            xr[4 * j + 0] = tv.x; xr[4 * j + 1] = tv.y;
            xr[4 * j + 2] = tv.z; xr[4 * j + 3] = tv.w;
        }

        // GPTQ 3-bit unpack (matches reference _unpack3 bit layout)
        #pragma unroll
        for (int i = 0; i < 32; ++i) {
            unsigned qv;
            if (i < 10)       qv = (r0 >> (3 * i)) & 7u;
            else if (i == 10) qv = ((r0 >> 30) & 3u) | ((r1 & 1u) << 2);
            else if (i < 21)  qv = (r1 >> (3 * (i - 11) + 1)) & 7u;
            else if (i == 21) qv = ((r1 >> 31) & 1u) | ((r2 & 3u) << 1);
            else              qv = (r2 >> (3 * (i - 22) + 2)) & 7u;
            acc[i & 3] += xr[i] * (float)qv;
        }

        r0 = n0; r1 = n1; r2 = n2;
        qp += (size_t)3 * OUTF;
        xg += 32;
    }
    psum[kc][col] = (acc[0] + acc[1]) + (acc[2] + acc[3]);
    __syncthreads();

    // ---- epilogue: 32 threads finalize the block's 32 columns ----
    if (t < COLS) {
        const int oo = obase + t;
        float a = 0.f;
        #pragma unroll
        for (int k = 0; k < KC; ++k) a += psum[k][t];

        float sx = 0.f;
        #pragma unroll
        for (int w = 0; w < BLK / 64; ++w) sx += wsum[w];

        // outlier dot: 64 f32 weights = 16 x 16B vector loads
        float od = 0.f;
        const float4* wv = (const float4*)(ow + (size_t)oo * NOUT);
        #pragma unroll
        for (int b = 0; b < 16; ++b) {
            float4 u = wv[b];
            od += u.x * xo[4 * b + 0] + u.y * xo[4 * b + 1]
                + u.z * xo[4 * b + 2] + u.w * xo[4 * b + 3];
        }

        out[oo] = scales[oo] * a - zeros[oo] * sx + bias[oo] + od;
    }
}

extern "C" void kernel_launch(void* const* d_in, const int* in_sizes, int n_in,
                              void* d_out, int out_size, void* d_ws, size_t ws_size,
                              hipStream_t stream) {
    const float* x  = (const float*)d_in[0];
    const int*   qw = (const int*)d_in[1];
    const float* sc = (const float*)d_in[2];
    const float* zr = (const float*)d_in[3];
    const float* bs = (const float*)d_in[4];
    const float* ow = (const float*)d_in[5];
    const int*   oi = (const int*)d_in[6];
    float*       y  = (float*)d_out;

    q3gemv<<<OUTF / COLS, BLK, 0, stream>>>(x, qw, sc, zr, bs, ow, oi, y);
}